// Round 13
// baseline (699.029 us; speedup 1.0000x reference)
//
#include <hip/hip_runtime.h>
#include <hip/hip_bf16.h>

#define BB 512
#define SS 1024
#define NI 20
#define HH 64
#define NG 256   // 4*H
#define MB4 4    // batch-dirs per lstm block (4 cells per lane, 1 chain-wave)
#define PAD 80   // h-row stride in f16
#define TROW 260 // x-table row stride (floats); [tok][unit][4tt], 16B rows

typedef unsigned short u16;
typedef unsigned int u32;
typedef unsigned long long u64;
typedef _Float16 f16;
typedef f16 f16x8 __attribute__((ext_vector_type(8)));
typedef float f32x4 __attribute__((ext_vector_type(4)));

#define LOG2E 1.4426950408889634f

__device__ __forceinline__ float bf2f(u16 b) { return __uint_as_float(((u32)b) << 16); }
// mode==1: data is bf16; mode==0: data is fp32
__device__ __forceinline__ float ldw(const void* p, int idx, int mode) {
  return mode ? bf2f(((const u16*)p)[idx]) : ((const float*)p)[idx];
}
__device__ __forceinline__ float frcp(float x) { return __builtin_amdgcn_rcpf(x); }
__device__ __forceinline__ float fexp2(float x) { return __builtin_amdgcn_exp2f(x); }

// ---- BiLSTM, barrier-free single-wave chain group. r12 ledger rewrite:
// ~65-70 us of total is FIXED harness overhead (r11/r12: no 2nd kernel yet
// total-dispatch = 63-71); r9's head is only ~12 us. The lever is the lstm
// dispatch (289.6). This round: r0's 4-wave step needed a barrier only
// because K=64 was SPLIT across waves. One wave can issue the whole group's
// 32 MFMAs (16 tiles x 2 K-halves -- IDENTICAL MFMA economy to r0's 4x8):
// lane (l,q) owns batch q, units {l,16+l,32+l,48+l}; A = 2 frags (4x dup
// rows, shared by all 16 tiles); B = full W_hh in-reg (128 VGPR); D-layout:
// lane (l,q) reg j = gate 16T+l of batch q (j = dup). h-exchange =
// wave-private LDS, lgkmcnt-ordered -- NO barrier, NO cross-wave wait
// (the ~250 cyc/step convergence cost of r0). wx read DURING the MFMA phase
// (latency hidden; no prefetch regs -> VGPR ~200-220). Waves 1-3 run
// extraction + x-table, then EXIT (freed; r10 lesson: no resident waiters).
// Conv co-residency (blocks 256..767) + fc head kernel: r9-verbatim.
// Weights prescaled: i,f,o rows by -log2e, g rows by +2log2e (exp2-ready).
union __align__(16) SharedU {
  struct __align__(16) {                 // ---- lstm branch (~30.5 KB)
    float table[21 * TROW];              // 21.8 KB; doubles as extract staging
    f16 h[MB4 * PAD];                    // single wave-private h buffer
    short tok_s[SS * MB4];               // [pos][m], stores tok+1
  } l;
  struct __align__(16) {                 // ---- conv branch (~27.2 KB)
    u32 stg[5120];                       // 20 KB extract staging
    float c1w[400];
    short tok_c[SS];                     // plain tok
    int redc[256];
    float pav[3][80];
    float avg[80];
    float cpart[2][100];
  } c;
};

__global__ __launch_bounds__(256)
void lstm_kernel(const void* in1,
                 const void* Wih_f, const void* Whh_f, const void* b_f,
                 const void* Wih_b, const void* Whh_b, const void* b_b,
                 const void* conv1_w, const void* conv2_w, const void* conv2_b,
                 float* hout, float* c2g) {
  int bx = blockIdx.x;
  int t = threadIdx.x;

  __shared__ SharedU sh;
  __shared__ int mode_sh;

  // ---- mode probe: b_f read as bf16; fp32 shows wild exponents ----
  if (t == 0) mode_sh = 1;
  __syncthreads();
  {
    float v = bf2f(((const u16*)b_f)[t]);
    if (!(fabsf(v) < 1000.0f)) atomicAnd(&mode_sh, 0);
  }
  __syncthreads();
  int mode = mode_sh;

  if (bx < 256) {
    // ================= LSTM branch =================
    auto& L = sh.l;
    int dir = bx >> 7;
    int b0 = (bx & 127) * MB4;
    int w = t >> 6, lane = t & 63, l = lane & 15, q = lane >> 4;
    const void* Wih = dir ? Wih_b : Wih_f;
    const void* Whh = dir ? Whh_b : Whh_f;
    const void* bv  = dir ? b_b   : b_f;

    // ---- token extraction for this block's 4 batches (r9-verbatim; all 4 waves) ----
    for (int m = 0; m < MB4; ++m) {
      if (mode) {
        u32* st = (u32*)L.table;
        for (int k0 = 0; k0 < 4; ++k0) {
          const u32* src = (const u32*)in1 + ((size_t)(b0 + m) * SS + k0 * 256) * 10;
#pragma unroll
          for (int i = 0; i < 10; ++i) st[t + i * 256] = src[t + i * 256];  // coalesced
          __syncthreads();
          const u32* row = st + t * 10;
          int tok = -1;
#pragma unroll
          for (int ww = 0; ww < 10; ++ww) {
            u32 u = row[ww];
            if (u & 0xFFFFu) tok = 2 * ww;
            if (u >> 16)     tok = 2 * ww + 1;
          }
          L.tok_s[(k0 * 256 + t) * MB4 + m] = (short)(tok + 1);
          __syncthreads();
        }
      } else {
        float4* st = (float4*)L.table;
        for (int k0 = 0; k0 < 4; ++k0) {
          const float4* src = (const float4*)((const float*)in1 + ((size_t)(b0 + m) * SS + k0 * 256) * 20);
#pragma unroll
          for (int i = 0; i < 5; ++i) st[t + i * 256] = src[t + i * 256];  // coalesced 16B/lane
          __syncthreads();
          const float* row = (const float*)L.table + t * 20;
          int tok = -1;
#pragma unroll
          for (int ww = 0; ww < 20; ++ww)
            if (row[ww] != 0.f) tok = ww;
          L.tok_s[(k0 * 256 + t) * MB4 + m] = (short)(tok + 1);
          __syncthreads();
        }
      }
    }

    // ---- x-projection table: table[tok+1][u][tt] = scl_tt*(W_ih[64tt+u][tok]+b); row 0 = bias ----
    for (int idx = t; idx < 21 * 256; idx += 256) {
      int r = idx >> 8, g = idx & 255;
      float scl = ((g >> 6) == 2) ? (2.f * LOG2E) : (-LOG2E);
      float v = ldw(bv, g, mode);
      if (r > 0) v += ldw(Wih, g * NI + (r - 1), mode);
      L.table[r * TROW + (g & 63) * 4 + (g >> 6)] = scl * v;
    }
    __syncthreads();      // last barrier; waves 1-3 exit below
    if (w != 0) return;

    // ================= chain wave (wave 0 only; barrier-free) =================
    // full W_hh in-reg: tile T covers gates 16T..16T+15 (tt = T>>2);
    // lane (l,q): B elem j = W[16T+l][kc*32 + 8q + j], prescaled.
    f16x8 Bf[16][2];
#pragma unroll
    for (int T = 0; T < 16; ++T) {
      float scl = ((T >> 2) == 2) ? (2.f * LOG2E) : (-LOG2E);
      int g = 16 * T + l;
#pragma unroll
      for (int kc = 0; kc < 2; ++kc) {
        f16x8 v;
#pragma unroll
        for (int j = 0; j < 8; ++j)
          v[j] = (f16)(scl * ldw(Whh, g * HH + kc * 32 + q * 8 + j, mode));
        Bf[T][kc] = v;
      }
    }
    f16* h16 = L.h;
    for (int i = lane; i < MB4 * PAD; i += 64) h16[i] = (f16)0.f;
    // (wave-private writes; compiler orders reads via lgkmcnt)

    int bsel = l >> 2;
    float d_st0 = 0.f, d_st1 = 0.f, d_st2 = 0.f, d_st3 = 0.f;  // d = 2log2e*c, 4 cells
    float hl0 = 0.f, hl1 = 0.f, hl2 = 0.f, hl3 = 0.f;

    int tokc, tok1;
    {
      int pos0 = dir ? (SS - 1) : 0;
      int pos1 = dir ? (SS - 2) : 1;
      tokc = (int)L.tok_s[pos0 * MB4 + q];
      tok1 = (int)L.tok_s[pos1 * MB4 + q];
    }
    const f32x4 Z = {0.f, 0.f, 0.f, 0.f};

#pragma unroll 1
    for (int s = 0; s < SS; ++s) {
      // critical path: own-wave h fragments (A[m][k=8q+j] = h[m>>2][k], 4x dup rows)
      f16x8 a0 = *(const f16x8*)&h16[bsel * PAD + 8 * q];
      f16x8 a1 = *(const f16x8*)&h16[bsel * PAD + 32 + 8 * q];
      // wx for CURRENT step: 4 cells x b128; latency hides under the MFMA phase
      f32x4 wx0 = *(const f32x4*)&L.table[tokc * TROW + (0 * 16 + l) * 4];
      f32x4 wx1 = *(const f32x4*)&L.table[tokc * TROW + (1 * 16 + l) * 4];
      f32x4 wx2 = *(const f32x4*)&L.table[tokc * TROW + (2 * 16 + l) * 4];
      f32x4 wx3 = *(const f32x4*)&L.table[tokc * TROW + (3 * 16 + l) * 4];
      // tok pipeline (1 ahead)
      {
        int pos2 = (dir ? (SS - 3 - s) : (s + 2)) & (SS - 1);  // wrapped values unused
        tokc = tok1;
        tok1 = (int)L.tok_s[pos2 * MB4 + q];
      }

      // 16 independent serial-C 2-chains (zero C-init); gv[T] = gate 16T+l, batch q
      float gv[16];
#pragma unroll
      for (int T = 0; T < 16; ++T) {
        f32x4 acc = __builtin_amdgcn_mfma_f32_16x16x32_f16(a0, Bf[T][0], Z, 0, 0, 0);
        acc = __builtin_amdgcn_mfma_f32_16x16x32_f16(a1, Bf[T][1], acc, 0, 0, 0);
        gv[T] = acc[0];
      }

      // 4 independent activation chains (cells c: unit c*16+l of batch q)
      // d-state form (r9-verified): Ei=e^-i, Ef=e^-f, Eo=e^-o, G=e^2g;
      // F=sigma(f); Itg=sigma(i)tanh(g); d' = F*d + 2log2e*Itg; h=tanh(c)sigma(o)
#define ACT(c, wxv, dst, hlv)                                            \
      {                                                                  \
        float Ei = fexp2(gv[c] + wxv[0]);                                \
        float Ef = fexp2(gv[4 + c] + wxv[1]);                            \
        float G  = fexp2(gv[8 + c] + wxv[2]);                            \
        float Eo = fexp2(gv[12 + c] + wxv[3]);                           \
        float F   = frcp(Ef + 1.f);                                      \
        float Itg = (G - 1.f) * frcp((Ei + 1.f) * (G + 1.f));            \
        float dnew = fmaf(F, dst, (2.f * LOG2E) * Itg);                  \
        dst = dnew;                                                      \
        float C = fexp2(dnew);                                           \
        float hv = (C - 1.f) * frcp((Eo + 1.f) * (C + 1.f));             \
        hlv = hv;                                                        \
        h16[q * PAD + c * 16 + l] = (f16)hv;                             \
      }
      ACT(0, wx0, d_st0, hl0)
      ACT(1, wx1, d_st1, hl1)
      ACT(2, wx2, d_st2, hl2)
      ACT(3, wx3, d_st3, hl3)
#undef ACT
    }
    hout[(b0 + q) * 128 + dir * 64 +  0 + l] = hl0;
    hout[(b0 + q) * 128 + dir * 64 + 16 + l] = hl1;
    hout[(b0 + q) * 128 + dir * 64 + 32 + l] = hl2;
    hout[(b0 + q) * 128 + dir * 64 + 48 + l] = hl3;

  } else {
    // ================= head conv branch (one batch; r9-verbatim) =================
    auto& C = sh.c;
    int b = bx - 256;
    // own extraction: plain tok per position + len
    int cnt = 0;
    if (mode) {
      for (int k0 = 0; k0 < 4; ++k0) {
        const u32* src = (const u32*)in1 + ((size_t)b * SS + k0 * 256) * 10;
#pragma unroll
        for (int i = 0; i < 10; ++i) C.stg[t + i * 256] = src[t + i * 256];  // coalesced
        __syncthreads();
        const u32* row = C.stg + t * 10;
        int tok = -1;
#pragma unroll
        for (int ww = 0; ww < 10; ++ww) {
          u32 u = row[ww];
          if (u & 0xFFFFu) tok = 2 * ww;
          if (u >> 16)     tok = 2 * ww + 1;
        }
        C.tok_c[k0 * 256 + t] = (short)tok;
        cnt += (tok >= 0);
        __syncthreads();
      }
    } else {
      float4* st = (float4*)C.stg;
      for (int k0 = 0; k0 < 4; ++k0) {
        const float4* src = (const float4*)((const float*)in1 + ((size_t)b * SS + k0 * 256) * 20);
#pragma unroll
        for (int i = 0; i < 5; ++i) st[t + i * 256] = src[t + i * 256];  // coalesced 16B/lane
        __syncthreads();
        const float* row = (const float*)C.stg + t * 20;
        int tok = -1;
#pragma unroll
        for (int ww = 0; ww < 20; ++ww)
          if (row[ww] != 0.f) tok = ww;
        C.tok_c[k0 * 256 + t] = (short)tok;
        cnt += (tok >= 0);
        __syncthreads();
      }
    }
    C.redc[t] = cnt;
    __syncthreads();
    for (int stp = 128; stp > 0; stp >>= 1) {
      if (t < stp) C.redc[t] += C.redc[t + stp];
      __syncthreads();
    }
    int len = C.redc[0];
    int bw = len >> 2;

    for (int i = t; i < 400; i += 256) C.c1w[i] = ldw(conv1_w, i, mode);
    __syncthreads();

    // ragged 4-bin mean: 240 threads = 80 (k,cc) units x 3 segments
    if (t < 240) {
      int seg = t / 80;
      int u = t - seg * 80;
      int k = u / 20, cc = u % 20;
      int base = k * bw;
      int s0 = base + (seg * bw) / 3;
      int s1 = base + ((seg + 1) * bw) / 3;
      float p0 = 0.f, p1 = 0.f, p2 = 0.f, p3 = 0.f;
      int s = s0;
      for (; s + 4 <= s1; s += 4) {
        // faithful torch reshape: flat f = s*20+cc of the [20,1024] map
        int f0 = s * 20 + cc, f1 = f0 + 20, f2 = f0 + 40, f3 = f0 + 60;
        int tk0 = C.tok_c[f0 & 1023];
        int tk1 = C.tok_c[f1 & 1023];
        int tk2 = C.tok_c[f2 & 1023];
        int tk3 = C.tok_c[f3 & 1023];
        if (tk0 >= 0) p0 += C.c1w[(f0 >> 10) * 20 + tk0];
        if (tk1 >= 0) p1 += C.c1w[(f1 >> 10) * 20 + tk1];
        if (tk2 >= 0) p2 += C.c1w[(f2 >> 10) * 20 + tk2];
        if (tk3 >= 0) p3 += C.c1w[(f3 >> 10) * 20 + tk3];
      }
      for (; s < s1; ++s) {
        int f = s * 20 + cc;
        int tk = C.tok_c[f & 1023];
        if (tk >= 0) p0 += C.c1w[(f >> 10) * 20 + tk];
      }
      C.pav[seg][u] = (p0 + p1) + (p2 + p3);
    }
    __syncthreads();
    if (t < 80) C.avg[t] = (C.pav[0][t] + C.pav[1][t] + C.pav[2][t]) / (float)bw;
    __syncthreads();

    // conv2: 200 threads = 100 outputs x 2 K-halves of 40
    if (t < 200) {
      int half = t / 100, o = t - half * 100;
      float dot = 0.f;
      int q0 = half * 40;
#pragma unroll 8
      for (int q = q0; q < q0 + 40; ++q)
        dot = fmaf(C.avg[q], ldw(conv2_w, o * 80 + q, mode), dot);
      C.cpart[half][o] = dot;
    }
    __syncthreads();
    if (t < 100) {
      float dot = C.cpart[0][t] + C.cpart[1][t] + ldw(conv2_b, t, mode);
      c2g[b * 100 + t] = dot > 0.f ? dot : 0.f;  // relu'd, biased
    }
  }
}

// ---- fc tail kernel (r9-verbatim): merged = [hout | c2] -> fc1 -> fc2 -> softmax ----
__global__ __launch_bounds__(256)
void head_kernel(const void* fc1_w, const void* fc1_b,
                 const void* fc2_w, const void* fc2_b,
                 const void* bvec, const float* hout, const float* c2g, void* out) {
  int b = blockIdx.x;
  int t = threadIdx.x;  // 256 threads
  __shared__ float merged[228];
  __shared__ float fpart[4][64];
  __shared__ float fc1v[64];
  __shared__ float f2p[2][64];
  __shared__ int mode_sh;

  if (t == 0) mode_sh = 1;
  __syncthreads();
  {
    float v = bf2f(((const u16*)bvec)[t]);
    if (!(fabsf(v) < 1000.0f)) atomicAnd(&mode_sh, 0);
  }
  __syncthreads();
  int mode = mode_sh;

  if (t < 128) merged[t] = hout[b * 128 + t];          // [h_fw | h_bw]
  else if (t < 228) merged[t] = c2g[b * 100 + (t - 128)];
  __syncthreads();

  // fc1: 256 threads = 64 outputs x 4 K-chunks of 57
  {
    int o = t & 63, ch = t >> 6;
    float v = 0.f;
    int m0 = ch * 57;
#pragma unroll 8
    for (int m = m0; m < m0 + 57; ++m)
      v = fmaf(merged[m], ldw(fc1_w, o * 228 + m, mode), v);
    fpart[ch][o] = v;
  }
  __syncthreads();
  if (t < 64)
    fc1v[t] = fpart[0][t] + fpart[1][t] + fpart[2][t] + fpart[3][t] + ldw(fc1_b, t, mode);
  __syncthreads();

  // fc2: 128 threads compute products, tree-reduce
  if (t < 128) {
    int o = t >> 6, m = t & 63;
    f2p[o][m] = fc1v[m] * ldw(fc2_w, o * 64 + m, mode);
  }
  __syncthreads();
  for (int stp = 32; stp > 0; stp >>= 1) {
    if (t < 128) {
      int o = t >> 6, m = t & 63;
      if (m < stp) f2p[o][m] += f2p[o][m + stp];
    }
    __syncthreads();
  }
  if (t == 0) {
    float x0 = f2p[0][0] + ldw(fc2_b, 0, mode);
    float x1 = f2p[1][0] + ldw(fc2_b, 1, mode);
    float mx = fmaxf(x0, x1);
    float e0 = fexp2(LOG2E * (x0 - mx)), e1 = fexp2(LOG2E * (x1 - mx));
    float inv = frcp(e0 + e1);
    if (mode) {
      ((__hip_bfloat16*)out)[b * 2 + 0] = __float2bfloat16(e0 * inv);
      ((__hip_bfloat16*)out)[b * 2 + 1] = __float2bfloat16(e1 * inv);
    } else {
      ((float*)out)[b * 2 + 0] = e0 * inv;
      ((float*)out)[b * 2 + 1] = e1 * inv;
    }
  }
}

extern "C" void kernel_launch(void* const* d_in, const int* in_sizes, int n_in,
                              void* d_out, int out_size, void* d_ws, size_t ws_size,
                              hipStream_t stream) {
  (void)in_sizes; (void)n_in; (void)out_size; (void)ws_size;
  char* ws = (char*)d_ws;
  float* hout = (float*)(ws + 256);                          // 256 KB
  float* c2g  = (float*)(ws + 256 + (size_t)BB * 128 * 4);   // 200 KB

  lstm_kernel<<<768, 256, 0, stream>>>(d_in[0],
                                       d_in[1], d_in[2], d_in[3],
                                       d_in[4], d_in[5], d_in[6],
                                       d_in[7], d_in[8], d_in[9],
                                       hout, c2g);
  head_kernel<<<BB, 256, 0, stream>>>(d_in[10], d_in[11], d_in[12], d_in[13],
                                      d_in[3], hout, c2g, d_out);
}

// Round 14
// 370.222 us; speedup vs baseline: 1.8881x; 1.8881x over previous
//
#include <hip/hip_runtime.h>
#include <hip/hip_bf16.h>

#define BB 512
#define SS 1024
#define NI 20
#define HH 64
#define NG 256   // 4*H
#define MB4 4    // batch-dirs per lstm block (1 cell per lane)
#define PAD 80   // h-row stride in f16
#define TROW 260 // x-table row stride (floats); [tok][unit][4tt], 16B rows

typedef unsigned short u16;
typedef unsigned int u32;
typedef unsigned long long u64;
typedef _Float16 f16;
typedef f16 f16x8 __attribute__((ext_vector_type(8)));
typedef float f32x4 __attribute__((ext_vector_type(4)));

#define LOG2E 1.4426950408889634f

__device__ __forceinline__ float bf2f(u16 b) { return __uint_as_float(((u32)b) << 16); }
// mode==1: data is bf16; mode==0: data is fp32
__device__ __forceinline__ float ldw(const void* p, int idx, int mode) {
  return mode ? bf2f(((const u16*)p)[idx]) : ((const float*)p)[idx];
}
__device__ __forceinline__ float frcp(float x) { return __builtin_amdgcn_rcpf(x); }
__device__ __forceinline__ float fexp2(float x) { return __builtin_amdgcn_exp2f(x); }

// ---- FINAL (r9 restore, best verified: 370.9 us total / 289.6 lstm).
// 14-round ledger: the 4-wave MB4 core is the optimum -- every structural
// alternative refuted by measurement (MB1 660, 8-wave 404, 1-chain/wave 509,
// dual-dir-in-lane 460, persistent consumers 429, inline-fc 377+tail,
// single-wave chain 619). The step is a sequential-recurrence latency floor
// (~640 cyc: barrier+LDS round trip ~250, MFMA ~60, activation ~110, issue
// ~220) with parallelism maxed at 4 issue ports; MfmaUtil 19 / VALU 35 /
// HBM 1.8% is the latency-bound signature, not a pipe roofline.
// blocks 0..255 = BiLSTM; 256..767 = head conv path (co-resident via LDS
// union -- r8-verified FREE). Loop bound compile-time SS (runtime trip count
// = +20 us, r7/r8). Step body: parallel-K MFMA pair (zero-C hoisted) +
// d-state activation (r9-verified -13 us) + b128 wx-table (bank conflicts
// -44%). Weights prescaled: i,f,o rows by -log2e, g rows by +2log2e.
union __align__(16) SharedU {
  struct __align__(16) {                 // ---- lstm branch (~31.3 KB)
    float table[21 * TROW];              // 21.8 KB; doubles as extract staging
    f16 hbuf[2][MB4][PAD];
    short tok_s[SS * MB4];               // [pos][m], stores tok+1
  } l;
  struct __align__(16) {                 // ---- conv branch (~27.2 KB)
    u32 stg[5120];                       // 20 KB extract staging
    float c1w[400];
    short tok_c[SS];                     // plain tok
    int redc[256];
    float pav[3][80];
    float avg[80];
    float cpart[2][100];
  } c;
};

__global__ __launch_bounds__(256)
void lstm_kernel(const void* in1,
                 const void* Wih_f, const void* Whh_f, const void* b_f,
                 const void* Wih_b, const void* Whh_b, const void* b_b,
                 const void* conv1_w, const void* conv2_w, const void* conv2_b,
                 float* hout, float* c2g) {
  int bx = blockIdx.x;
  int t = threadIdx.x;

  __shared__ SharedU sh;
  __shared__ int mode_sh;

  // ---- mode probe: b_f read as bf16; fp32 shows wild exponents ----
  if (t == 0) mode_sh = 1;
  __syncthreads();
  {
    float v = bf2f(((const u16*)b_f)[t]);
    if (!(fabsf(v) < 1000.0f)) atomicAnd(&mode_sh, 0);
  }
  __syncthreads();
  int mode = mode_sh;

  if (bx < 256) {
    // ================= LSTM branch =================
    auto& L = sh.l;
    int dir = bx >> 7;
    int b0 = (bx & 127) * MB4;
    int w = t >> 6, lane = t & 63, l = lane & 15, q = lane >> 4;
    int bsel = l >> 2;            // batch whose h this lane's A-row carries
    const void* Wih = dir ? Wih_b : Wih_f;
    const void* Whh = dir ? Whh_b : Whh_f;
    const void* bv  = dir ? b_b   : b_f;

    // ---- token extraction for this block's 4 batches (staged through table) ----
    for (int m = 0; m < MB4; ++m) {
      if (mode) {
        u32* st = (u32*)L.table;
        for (int k0 = 0; k0 < 4; ++k0) {
          const u32* src = (const u32*)in1 + ((size_t)(b0 + m) * SS + k0 * 256) * 10;
#pragma unroll
          for (int i = 0; i < 10; ++i) st[t + i * 256] = src[t + i * 256];  // coalesced
          __syncthreads();
          const u32* row = st + t * 10;
          int tok = -1;
#pragma unroll
          for (int ww = 0; ww < 10; ++ww) {
            u32 u = row[ww];
            if (u & 0xFFFFu) tok = 2 * ww;
            if (u >> 16)     tok = 2 * ww + 1;
          }
          L.tok_s[(k0 * 256 + t) * MB4 + m] = (short)(tok + 1);
          __syncthreads();
        }
      } else {
        float4* st = (float4*)L.table;
        for (int k0 = 0; k0 < 4; ++k0) {
          const float4* src = (const float4*)((const float*)in1 + ((size_t)(b0 + m) * SS + k0 * 256) * 20);
#pragma unroll
          for (int i = 0; i < 5; ++i) st[t + i * 256] = src[t + i * 256];  // coalesced 16B/lane
          __syncthreads();
          const float* row = (const float*)L.table + t * 20;
          int tok = -1;
#pragma unroll
          for (int ww = 0; ww < 20; ++ww)
            if (row[ww] != 0.f) tok = ww;
          L.tok_s[(k0 * 256 + t) * MB4 + m] = (short)(tok + 1);
          __syncthreads();
        }
      }
    }

    // ---- x-projection table: table[tok+1][u][tt] = scl_tt*(W_ih[64tt+u][tok]+b); row 0 = bias ----
    for (int idx = t; idx < 21 * 256; idx += 256) {
      int r = idx >> 8, g = idx & 255;
      float scl = ((g >> 6) == 2) ? (2.f * LOG2E) : (-LOG2E);
      float v = ldw(bv, g, mode);
      if (r > 0) v += ldw(Wih, g * NI + (r - 1), mode);
      L.table[r * TROW + (g & 63) * 4 + (g >> 6)] = scl * v;
    }
    // ---- W_hh B-fragments: n=lane&15 -> gate col (unit 16w+l, type tt), k=q*8+j ----
    f16x8 Bf[4][2];
#pragma unroll
    for (int tt = 0; tt < 4; ++tt) {
      float scl = (tt == 2) ? (2.f * LOG2E) : (-LOG2E);
      int g = 64 * tt + 16 * w + l;
#pragma unroll
      for (int kc = 0; kc < 2; ++kc) {
        f16x8 v;
#pragma unroll
        for (int j = 0; j < 8; ++j)
          v[j] = (f16)(scl * ldw(Whh, g * HH + kc * 32 + q * 8 + j, mode));
        Bf[tt][kc] = v;
      }
    }
    for (int idx = t; idx < 2 * MB4 * PAD; idx += 256)
      ((f16*)L.hbuf)[idx] = (f16)0.f;
    __syncthreads();

    float d_st = 0.f, hlast = 0.f;   // d = 2*log2e*c
    int jj = 16 * w + l;

    // x-pipeline prologue: wx for s=0 (regs), tok for s=1 (reg)
    f32x4 wxc;
    {
      int pos0 = dir ? (SS - 1) : 0;
      wxc = *(const f32x4*)&L.table[(int)L.tok_s[pos0 * MB4 + q] * TROW + jj * 4];
    }
    int tok1;
    {
      int pos1 = dir ? (SS - 2) : 1;
      tok1 = (int)L.tok_s[pos1 * MB4 + q];
    }

    const f32x4 Z = {0.f, 0.f, 0.f, 0.f};

#pragma unroll 2
    for (int s = 0; s < SS; ++s) {
      int p = s & 1;
      // critical path: h fragments (A[m=l][k=q*8+j] = h[bsel][k], 4x dup rows)
      f16x8 a0 = *(const f16x8*)&L.hbuf[p][bsel][q * 8];
      f16x8 a1 = *(const f16x8*)&L.hbuf[p][bsel][32 + q * 8];
      // off-path: wx prefetch for s+1 (single b128), tok fetch for s+2
      f32x4 wxn = *(const f32x4*)&L.table[tok1 * TROW + jj * 4];
      {
        int pos2 = (dir ? (SS - 3 - s) : (s + 2)) & (SS - 1);  // wrapped values unused
        tok1 = (int)L.tok_s[pos2 * MB4 + q];
      }

      // parallel-K MFMA pair per gate type (zero-C hoisted; one dependent MFMA
      // latency removed from the pole; gates assembled by scalar adds)
      f32x4 accA[4], accB[4];
#pragma unroll
      for (int tt = 0; tt < 4; ++tt)
        accA[tt] = __builtin_amdgcn_mfma_f32_16x16x32_f16(a0, Bf[tt][0], Z, 0, 0, 0);
#pragma unroll
      for (int tt = 0; tt < 4; ++tt)
        accB[tt] = __builtin_amdgcn_mfma_f32_16x16x32_f16(a1, Bf[tt][1], Z, 0, 0, 0);

      float g_i = accA[0][0] + accB[0][0] + wxc[0];
      float g_f = accA[1][0] + accB[1][0] + wxc[1];
      float g_g = accA[2][0] + accB[2][0] + wxc[2];
      float g_o = accA[3][0] + accB[3][0] + wxc[3];

      // d-state activation: Ei=e^-i, Ef=e^-f, Eo=e^-o, G=e^2g; F=sigma(f);
      // Itg=sigma(i)*tanh(g); d' = F*d + 2log2e*Itg; h = tanh(c)*sigma(o)
      {
        float Ei = fexp2(g_i);
        float Ef = fexp2(g_f);
        float G  = fexp2(g_g);
        float Eo = fexp2(g_o);
        float F   = frcp(Ef + 1.f);
        float Itg = (G - 1.f) * frcp((Ei + 1.f) * (G + 1.f));
        float dnew = fmaf(F, d_st, (2.f * LOG2E) * Itg);
        d_st = dnew;
        float C = fexp2(dnew);
        float hv = (C - 1.f) * frcp((Eo + 1.f) * (C + 1.f));
        hlast = hv;
        L.hbuf[p ^ 1][q][jj] = (f16)hv;
      }
      __syncthreads();
      wxc = wxn;
    }
    hout[(b0 + q) * 128 + dir * 64 + jj] = hlast;

  } else {
    // ================= head conv branch (one batch; r8-verified) =================
    auto& C = sh.c;
    int b = bx - 256;
    // own extraction: plain tok per position + len
    int cnt = 0;
    if (mode) {
      for (int k0 = 0; k0 < 4; ++k0) {
        const u32* src = (const u32*)in1 + ((size_t)b * SS + k0 * 256) * 10;
#pragma unroll
        for (int i = 0; i < 10; ++i) C.stg[t + i * 256] = src[t + i * 256];  // coalesced
        __syncthreads();
        const u32* row = C.stg + t * 10;
        int tok = -1;
#pragma unroll
        for (int ww = 0; ww < 10; ++ww) {
          u32 u = row[ww];
          if (u & 0xFFFFu) tok = 2 * ww;
          if (u >> 16)     tok = 2 * ww + 1;
        }
        C.tok_c[k0 * 256 + t] = (short)tok;
        cnt += (tok >= 0);
        __syncthreads();
      }
    } else {
      float4* st = (float4*)C.stg;
      for (int k0 = 0; k0 < 4; ++k0) {
        const float4* src = (const float4*)((const float*)in1 + ((size_t)b * SS + k0 * 256) * 20);
#pragma unroll
        for (int i = 0; i < 5; ++i) st[t + i * 256] = src[t + i * 256];  // coalesced 16B/lane
        __syncthreads();
        const float* row = (const float*)C.stg + t * 20;
        int tok = -1;
#pragma unroll
        for (int ww = 0; ww < 20; ++ww)
          if (row[ww] != 0.f) tok = ww;
        C.tok_c[k0 * 256 + t] = (short)tok;
        cnt += (tok >= 0);
        __syncthreads();
      }
    }
    C.redc[t] = cnt;
    __syncthreads();
    for (int stp = 128; stp > 0; stp >>= 1) {
      if (t < stp) C.redc[t] += C.redc[t + stp];
      __syncthreads();
    }
    int len = C.redc[0];
    int bw = len >> 2;

    for (int i = t; i < 400; i += 256) C.c1w[i] = ldw(conv1_w, i, mode);
    __syncthreads();

    // ragged 4-bin mean: 240 threads = 80 (k,cc) units x 3 segments
    if (t < 240) {
      int seg = t / 80;
      int u = t - seg * 80;
      int k = u / 20, cc = u % 20;
      int base = k * bw;
      int s0 = base + (seg * bw) / 3;
      int s1 = base + ((seg + 1) * bw) / 3;
      float p0 = 0.f, p1 = 0.f, p2 = 0.f, p3 = 0.f;
      int s = s0;
      for (; s + 4 <= s1; s += 4) {
        // faithful torch reshape: flat f = s*20+cc of the [20,1024] map
        int f0 = s * 20 + cc, f1 = f0 + 20, f2 = f0 + 40, f3 = f0 + 60;
        int tk0 = C.tok_c[f0 & 1023];
        int tk1 = C.tok_c[f1 & 1023];
        int tk2 = C.tok_c[f2 & 1023];
        int tk3 = C.tok_c[f3 & 1023];
        if (tk0 >= 0) p0 += C.c1w[(f0 >> 10) * 20 + tk0];
        if (tk1 >= 0) p1 += C.c1w[(f1 >> 10) * 20 + tk1];
        if (tk2 >= 0) p2 += C.c1w[(f2 >> 10) * 20 + tk2];
        if (tk3 >= 0) p3 += C.c1w[(f3 >> 10) * 20 + tk3];
      }
      for (; s < s1; ++s) {
        int f = s * 20 + cc;
        int tk = C.tok_c[f & 1023];
        if (tk >= 0) p0 += C.c1w[(f >> 10) * 20 + tk];
      }
      C.pav[seg][u] = (p0 + p1) + (p2 + p3);
    }
    __syncthreads();
    if (t < 80) C.avg[t] = (C.pav[0][t] + C.pav[1][t] + C.pav[2][t]) / (float)bw;
    __syncthreads();

    // conv2: 200 threads = 100 outputs x 2 K-halves of 40
    if (t < 200) {
      int half = t / 100, o = t - half * 100;
      float dot = 0.f;
      int q0 = half * 40;
#pragma unroll 8
      for (int q = q0; q < q0 + 40; ++q)
        dot = fmaf(C.avg[q], ldw(conv2_w, o * 80 + q, mode), dot);
      C.cpart[half][o] = dot;
    }
    __syncthreads();
    if (t < 100) {
      float dot = C.cpart[0][t] + C.cpart[1][t] + ldw(conv2_b, t, mode);
      c2g[b * 100 + t] = dot > 0.f ? dot : 0.f;  // relu'd, biased
    }
  }
}

// ---- fc tail: merged = [hout | c2] -> fc1 -> fc2 -> softmax ----
__global__ __launch_bounds__(256)
void head_kernel(const void* fc1_w, const void* fc1_b,
                 const void* fc2_w, const void* fc2_b,
                 const void* bvec, const float* hout, const float* c2g, void* out) {
  int b = blockIdx.x;
  int t = threadIdx.x;  // 256 threads
  __shared__ float merged[228];
  __shared__ float fpart[4][64];
  __shared__ float fc1v[64];
  __shared__ float f2p[2][64];
  __shared__ int mode_sh;

  if (t == 0) mode_sh = 1;
  __syncthreads();
  {
    float v = bf2f(((const u16*)bvec)[t]);
    if (!(fabsf(v) < 1000.0f)) atomicAnd(&mode_sh, 0);
  }
  __syncthreads();
  int mode = mode_sh;

  if (t < 128) merged[t] = hout[b * 128 + t];          // [h_fw | h_bw]
  else if (t < 228) merged[t] = c2g[b * 100 + (t - 128)];
  __syncthreads();

  // fc1: 256 threads = 64 outputs x 4 K-chunks of 57
  {
    int o = t & 63, ch = t >> 6;
    float v = 0.f;
    int m0 = ch * 57;
#pragma unroll 8
    for (int m = m0; m < m0 + 57; ++m)
      v = fmaf(merged[m], ldw(fc1_w, o * 228 + m, mode), v);
    fpart[ch][o] = v;
  }
  __syncthreads();
  if (t < 64)
    fc1v[t] = fpart[0][t] + fpart[1][t] + fpart[2][t] + fpart[3][t] + ldw(fc1_b, t, mode);
  __syncthreads();

  // fc2: 128 threads compute products, tree-reduce
  if (t < 128) {
    int o = t >> 6, m = t & 63;
    f2p[o][m] = fc1v[m] * ldw(fc2_w, o * 64 + m, mode);
  }
  __syncthreads();
  for (int stp = 32; stp > 0; stp >>= 1) {
    if (t < 128) {
      int o = t >> 6, m = t & 63;
      if (m < stp) f2p[o][m] += f2p[o][m + stp];
    }
    __syncthreads();
  }
  if (t == 0) {
    float x0 = f2p[0][0] + ldw(fc2_b, 0, mode);
    float x1 = f2p[1][0] + ldw(fc2_b, 1, mode);
    float mx = fmaxf(x0, x1);
    float e0 = fexp2(LOG2E * (x0 - mx)), e1 = fexp2(LOG2E * (x1 - mx));
    float inv = frcp(e0 + e1);
    if (mode) {
      ((__hip_bfloat16*)out)[b * 2 + 0] = __float2bfloat16(e0 * inv);
      ((__hip_bfloat16*)out)[b * 2 + 1] = __float2bfloat16(e1 * inv);
    } else {
      ((float*)out)[b * 2 + 0] = e0 * inv;
      ((float*)out)[b * 2 + 1] = e1 * inv;
    }
  }
}

extern "C" void kernel_launch(void* const* d_in, const int* in_sizes, int n_in,
                              void* d_out, int out_size, void* d_ws, size_t ws_size,
                              hipStream_t stream) {
  (void)in_sizes; (void)n_in; (void)out_size; (void)ws_size;
  char* ws = (char*)d_ws;
  float* hout = (float*)(ws + 256);                          // 256 KB
  float* c2g  = (float*)(ws + 256 + (size_t)BB * 128 * 4);   // 200 KB

  lstm_kernel<<<768, 256, 0, stream>>>(d_in[0],
                                       d_in[1], d_in[2], d_in[3],
                                       d_in[4], d_in[5], d_in[6],
                                       d_in[7], d_in[8], d_in[9],
                                       hout, c2g);
  head_kernel<<<BB, 256, 0, stream>>>(d_in[10], d_in[11], d_in[12], d_in[13],
                                      d_in[3], hout, c2g, d_out);
}